// Round 1
// baseline (738.744 us; speedup 1.0000x reference)
//
#include <hip/hip_runtime.h>
#include <math.h>

#define BB 32
#define LL 40
#define DD 128
#define NLAYER 2

// tanh via exp2-based fast exp; clamp to avoid inf/inf
__device__ __forceinline__ float tanh_fast(float x) {
    x = fminf(fmaxf(x, -15.f), 15.f);
    float e = __expf(2.f * x);
    return (e - 1.f) / (e + 1.f);
}

__device__ __forceinline__ float sigmoid_fast(float x) {
    return 1.f / (1.f + __expf(-x));
}

// Compute 1/(||embed[idx]||^2 + 1e-4) for all (seq, b, l)
__global__ void inv_kernel(const int* __restrict__ q, const int* __restrict__ a,
                           const float* __restrict__ embed, float* __restrict__ inv) {
    int gid = blockIdx.x * 4 + (threadIdx.x >> 6);   // one wave per row
    int lane = threadIdx.x & 63;
    if (gid >= 2 * BB * LL) return;
    int s = gid / (BB * LL);
    int r = gid % (BB * LL);
    const int* idx = s ? a : q;
    int e = idx[r];
    const float* row = embed + (size_t)e * DD;
    float v0 = row[lane], v1 = row[lane + 64];
    float d = v0 * v0 + v1 * v1;
    #pragma unroll
    for (int o = 32; o > 0; o >>= 1) d += __shfl_down(d, o);
    if (lane == 0) inv[gid] = 1.f / (d + 1e-4f);
}

// One pipelined step: blockIdx.z==0 -> layer1 at step t (density input),
//                     blockIdx.z==1 -> layer2 at step t-1 (global xt input, maxpool out)
// h1/h2: [2 pingpong][2 seq][B*D*D]; c1/c2: [2 seq][B*D*D]; pool: [2 seq][B*D*D]
__launch_bounds__(256)
__global__ void step_kernel(const float* __restrict__ embed,
                            const int* __restrict__ q,
                            const int* __restrict__ a,
                            const float* __restrict__ inv,
                            const float* __restrict__ conv_w,
                            const float* __restrict__ conv_b,
                            float* __restrict__ h1,
                            float* __restrict__ c1,
                            float* __restrict__ h2,
                            float* __restrict__ c2,
                            float* __restrict__ pool,
                            int t) {
    const int stage = blockIdx.z;            // 0: layer1 step t; 1: layer2 step t-1
    const int u = stage ? (t - 1) : t;
    if (u < 0 || u >= LL) return;            // uniform per block

    const int sb = blockIdx.y;               // 0..63
    const int s = sb >> 5, b = sb & 31;
    const int bx = blockIdx.x;               // 0..63 => output rows 2*bx, 2*bx+1
    const int tx = threadIdx.x;              // 0..127 (output col)
    const int ty = threadIdx.y;              // 0..1
    const int tid = ty * 128 + tx;

    __shared__ float win[6][DD];
    __shared__ float xe_s[DD];
    __shared__ float wls[48];
    __shared__ float bls[4];

    const int li = stage;                    // layer index
    if (tid < 48) wls[tid] = conv_w[li * 48 + tid];
    if (tid < 4)  bls[tid] = conv_b[li * 4 + tid];

    const size_t SEQBDD = (size_t)2 * BB * DD * DD;   // one pingpong bank (both seqs)
    const size_t bdd = (size_t)(s * BB + b) * (DD * DD);
    const int pp_out = u & 1, pp_in = pp_out ^ 1;

    const float* h_in;
    float* h_out;
    float* c_buf;
    const float* xt = nullptr;
    float inv_bt = 0.f;

    if (stage == 0) {
        h_in  = h1 + (size_t)pp_in  * SEQBDD + bdd;
        h_out = h1 + (size_t)pp_out * SEQBDD + bdd;
        c_buf = c1 + bdd;
        const int* idx = s ? a : q;
        int e = idx[b * LL + u];
        if (tid < DD) xe_s[tid] = embed[(size_t)e * DD + tid];
        inv_bt = inv[s * (BB * LL) + b * LL + u];
    } else {
        xt    = h1 + (size_t)pp_out * SEQBDD + bdd;   // layer1 output at step u
        h_in  = h2 + (size_t)pp_in  * SEQBDD + bdd;
        h_out = h2 + (size_t)pp_out * SEQBDD + bdd;
        c_buf = c2 + bdd;
    }
    __syncthreads();   // xe_s, wls, bls ready

    const bool first = (u == 0);
    // Window rows r0..r0+5 of the concat [xt(128 rows); h(128 rows)], r0 = 4*bx-1
    const int r0 = 4 * bx - 1;
    #pragma unroll
    for (int e2 = 0; e2 < 3; ++e2) {
        int i = tid + e2 * 256;
        int wr = i >> 7, col = i & 127;
        int r = r0 + wr;
        float v = 0.f;
        if (r >= 0 && r < 256) {
            if (r < 128) {
                v = (stage == 0) ? xe_s[r] * xe_s[col] * inv_bt
                                 : xt[r * DD + col];
            } else {
                v = first ? 0.f : h_in[(r - 128) * DD + col];
            }
        }
        win[wr][col] = v;
    }
    __syncthreads();

    float acc0 = bls[0], acc1 = bls[1], acc2 = bls[2], acc3 = bls[3];
    #pragma unroll
    for (int kh = 0; kh < 4; ++kh) {
        int wr = 2 * ty + kh;
        #pragma unroll
        for (int kw = 0; kw < 3; ++kw) {
            int cw = tx - 1 + kw;
            float v = (cw >= 0 && cw < 128) ? win[wr][cw] : 0.f;
            acc0 += v * wls[0 * 12 + kh * 3 + kw];
            acc1 += v * wls[1 * 12 + kh * 3 + kw];
            acc2 += v * wls[2 * 12 + kh * 3 + kw];
            acc3 += v * wls[3 * 12 + kh * 3 + kw];
        }
    }

    float fg = sigmoid_fast(acc0);
    float ig = sigmoid_fast(acc1);
    float og = sigmoid_fast(acc2);
    float cs = tanh_fast(acc3);

    const int oh = 2 * bx + ty;
    const int px = oh * DD + tx;
    float c_old = first ? 0.f : c_buf[px];
    float cn = fg * c_old + ig * cs;
    float hn = og * tanh_fast(cn);
    c_buf[px] = cn;
    h_out[px] = hn;

    if (stage == 1) {
        float* pl = pool + bdd;
        pl[px] = first ? hn : fmaxf(pl[px], hn);
    }
}

// score = qa @ lin_w.T + lin_b; out = log_softmax(score)
__global__ void final_kernel(const float* __restrict__ pool,   // [2 seq][B][D*D]
                             const float* __restrict__ lin_w,  // [2][2*D*D]
                             const float* __restrict__ lin_b,  // [2]
                             float* __restrict__ out) {
    const int b = blockIdx.x;
    const int tid = threadIdx.x;  // 256
    const int DD2 = DD * DD;
    const float* pq = pool + (size_t)b * DD2;
    const float* pa = pool + (size_t)(BB + b) * DD2;
    float s0 = 0.f, s1 = 0.f;
    for (int j = tid; j < DD2; j += 256) {
        float vq = pq[j], va = pa[j];
        s0 += vq * lin_w[j]            + va * lin_w[DD2 + j];
        s1 += vq * lin_w[2 * DD2 + j]  + va * lin_w[3 * DD2 + j];
    }
    #pragma unroll
    for (int o = 32; o > 0; o >>= 1) {
        s0 += __shfl_down(s0, o);
        s1 += __shfl_down(s1, o);
    }
    __shared__ float sh0[4], sh1[4];
    int wid = tid >> 6, lane = tid & 63;
    if (lane == 0) { sh0[wid] = s0; sh1[wid] = s1; }
    __syncthreads();
    if (tid == 0) {
        float a0 = sh0[0] + sh0[1] + sh0[2] + sh0[3] + lin_b[0];
        float a1 = sh1[0] + sh1[1] + sh1[2] + sh1[3] + lin_b[1];
        float m = fmaxf(a0, a1);
        float lse = m + logf(expf(a0 - m) + expf(a1 - m));
        out[b * 2 + 0] = a0 - lse;
        out[b * 2 + 1] = a1 - lse;
    }
}

extern "C" void kernel_launch(void* const* d_in, const int* in_sizes, int n_in,
                              void* d_out, int out_size, void* d_ws, size_t ws_size,
                              hipStream_t stream) {
    const int*   q      = (const int*)d_in[0];
    const int*   a      = (const int*)d_in[1];
    const float* embed  = (const float*)d_in[2];
    const float* conv_w = (const float*)d_in[3];
    const float* conv_b = (const float*)d_in[4];
    const float* lin_w  = (const float*)d_in[5];
    const float* lin_b  = (const float*)d_in[6];
    float* out = (float*)d_out;

    // Workspace layout (floats). SEQBDD = 2*B*D*D = 1,048,576 floats (4 MB).
    // inv: 2*B*L | h1: 2*SEQBDD | c1: SEQBDD | h2: 2*SEQBDD | c2: SEQBDD | pool: SEQBDD
    // total ~= 29.4 MB
    const size_t SEQBDD = (size_t)2 * BB * DD * DD;
    float* ws   = (float*)d_ws;
    float* inv  = ws;
    float* h1   = inv + 2 * BB * LL;
    float* c1   = h1 + 2 * SEQBDD;
    float* h2   = c1 + SEQBDD;
    float* c2   = h2 + 2 * SEQBDD;
    float* pool = c2 + SEQBDD;

    inv_kernel<<<(2 * BB * LL + 3) / 4, 256, 0, stream>>>(q, a, embed, inv);

    dim3 block(128, 2);
    dim3 grid(64, 64, 2);   // 64 row-pairs, 2seq*32batch, 2 pipeline stages
    for (int t = 0; t <= LL; ++t) {
        step_kernel<<<grid, block, 0, stream>>>(embed, q, a, inv, conv_w, conv_b,
                                                h1, c1, h2, c2, pool, t);
    }

    final_kernel<<<BB, 256, 0, stream>>>(pool, lin_w, lin_b, out);
}